// Round 1
// baseline (2405.314 us; speedup 1.0000x reference)
//
#include <hip/hip_runtime.h>
#include <math.h>

// Problem constants
#define B_   4096
#define N_   64
#define D_   12
#define SS_  5
#define I_   7
#define H_   256
#define G4_  1024   // 4*H
#define M1_  512
#define M2_  512
#define A_   81

__device__ __forceinline__ void fma4(float4& a, float s, const float4 w) {
  a.x = fmaf(s, w.x, a.x);
  a.y = fmaf(s, w.y, a.y);
  a.z = fmaf(s, w.z, a.z);
  a.w = fmaf(s, w.w, a.w);
}

__device__ __forceinline__ float4 relu4(float4 v) {
  v.x = fmaxf(v.x, 0.f); v.y = fmaxf(v.y, 0.f);
  v.z = fmaxf(v.z, 0.f); v.w = fmaxf(v.w, 0.f);
  return v;
}

// ---------------------------------------------------------------------------
// Kernel 0: pack LSTM weights.
// Wp_hh[k][ju][g] = W_hh[g*256+ju][k]   (k-major, gates of one unit contiguous)
// Wp_ih[f][ju][g] = W_ih[g*256+ju][f]
// bsum[ju][g]     = b_ih[g*256+ju] + b_hh[g*256+ju]
// ---------------------------------------------------------------------------
__global__ void pack_weights(const float* __restrict__ W_ih,
                             const float* __restrict__ W_hh,
                             const float* __restrict__ b_ih,
                             const float* __restrict__ b_hh,
                             float* __restrict__ Wp_hh,
                             float* __restrict__ Wp_ih,
                             float* __restrict__ bsum) {
  const int idx = blockIdx.x * blockDim.x + threadIdx.x;
  if (idx < H_ * G4_) {                 // 262144
    const int k  = idx >> 10;
    const int r  = idx & 1023;
    const int ju = r >> 2;
    const int g  = r & 3;
    Wp_hh[idx] = W_hh[(g * H_ + ju) * H_ + k];
  }
  if (idx < I_ * G4_) {                 // 7168
    const int f  = idx >> 10;
    const int r  = idx & 1023;
    const int ju = r >> 2;
    const int g  = r & 3;
    Wp_ih[idx] = W_ih[(g * H_ + ju) * I_ + f];
  }
  if (idx < G4_) {                      // 1024
    const int ju = idx >> 2;
    const int g  = idx & 3;
    const int j  = g * H_ + ju;
    bsum[idx] = b_ih[j] + b_hh[j];
  }
}

// ---------------------------------------------------------------------------
// Kernel 1: distance + stable descending rank-sort + gather.
// xbuf layout: [t][B][7]  (so LSTM step t reads a contiguous 112-float slab
// per 16-batch block). selfbuf: [B][5] = state[:,0,:5] (pre-sort entity 0).
// ---------------------------------------------------------------------------
__global__ void sort_gather(const float* __restrict__ state,
                            float* __restrict__ xbuf,
                            float* __restrict__ selfbuf) {
  const int b = blockIdx.x;
  const int e = threadIdx.x;                 // 0..63, one wave
  const float* row = state + ((size_t)b * N_ + e) * D_;
  const float4* r4 = (const float4*)row;     // rows are 48B-aligned
  const float4 v0 = r4[0], v1 = r4[1], v2 = r4[2];
  float s[12];
  s[0]=v0.x; s[1]=v0.y; s[2]=v0.z;  s[3]=v0.w;
  s[4]=v1.x; s[5]=v1.y; s[6]=v1.z;  s[7]=v1.w;
  s[8]=v2.x; s[9]=v2.y; s[10]=v2.z; s[11]=v2.w;

  const float s5 = s[5], s6 = s[6];
  const float d = (s5 != 0.f && s6 != 0.f) ? sqrtf(s5 * s5 + s6 * s6) : INFINITY;

  __shared__ float dd[64];
  dd[e] = d;
  __syncthreads();

  // stable descending rank: position = #{j : d_j > d_e  or (d_j == d_e and j < e)}
  int rank = 0;
  #pragma unroll
  for (int j = 0; j < 64; ++j) {
    const float dj = dd[j];
    rank += (dj > d || (dj == d && j < e)) ? 1 : 0;
  }

  float* xo = xbuf + ((size_t)rank * B_ + b) * I_;
  #pragma unroll
  for (int f = 0; f < I_; ++f) xo[f] = s[SS_ + f];

  if (e == 0) {
    #pragma unroll
    for (int i = 0; i < SS_; ++i) selfbuf[b * SS_ + i] = s[i];
  }
}

// ---------------------------------------------------------------------------
// Kernel 2: LSTM. 256 blocks x 512 threads; block owns 16 batches for all 64
// steps (no cross-block sync needed). Thread (bg=tid>>7, jg=tid&127) computes
// gates for 4 batches x 2 hidden units; acc float4 = (i,f,g,o) of one unit,
// so c stays in registers and h round-trips only through LDS.
// ---------------------------------------------------------------------------
__global__ __launch_bounds__(512) void lstm_kernel(
    const float* __restrict__ xbuf,
    const float* __restrict__ Wp_hh,
    const float* __restrict__ Wp_ih,
    const float* __restrict__ bsum,
    float* __restrict__ hnbuf) {
  const int tid = threadIdx.x;
  const int jg  = tid & 127;
  const int bg  = tid >> 7;             // 0..3
  const int b0  = blockIdx.x << 4;      // 16 batches per block

  __shared__ float h_s[16][H_];
  __shared__ float x_s[16 * I_];

  for (int i = tid; i < 16 * H_; i += 512) ((float*)h_s)[i] = 0.f;

  const float4* __restrict__ Wp4 = (const float4*)Wp_hh;  // [256][256] float4
  const float4* __restrict__ Wi4 = (const float4*)Wp_ih;  // [7][256]  float4
  const float4* bs4 = (const float4*)bsum;                // [256]     float4
  const float4 bias0 = bs4[jg];
  const float4 bias1 = bs4[jg + 128];

  float c_[4][2];
  #pragma unroll
  for (int q = 0; q < 4; ++q) { c_[q][0] = 0.f; c_[q][1] = 0.f; }

  for (int t = 0; t < 64; ++t) {
    if (tid < 16 * I_) x_s[tid] = xbuf[t * (B_ * I_) + b0 * I_ + tid];
    __syncthreads();   // x ready; prev-step h writes visible

    float4 acc[4][2];
    #pragma unroll
    for (int q = 0; q < 4; ++q) { acc[q][0] = bias0; acc[q][1] = bias1; }

    // input contribution, K=7
    #pragma unroll
    for (int f = 0; f < I_; ++f) {
      const float4 w0 = Wi4[f * 256 + jg];
      const float4 w1 = Wi4[f * 256 + jg + 128];
      #pragma unroll
      for (int q = 0; q < 4; ++q) {
        const float xv = x_s[((bg << 2) + q) * I_ + f];
        fma4(acc[q][0], xv, w0);
        fma4(acc[q][1], xv, w1);
      }
    }

    // hidden contribution, K=256, unrolled by 4
    for (int k = 0; k < H_; k += 4) {
      const float4 w00 = Wp4[(k + 0) * 256 + jg];
      const float4 w01 = Wp4[(k + 0) * 256 + jg + 128];
      const float4 w10 = Wp4[(k + 1) * 256 + jg];
      const float4 w11 = Wp4[(k + 1) * 256 + jg + 128];
      const float4 w20 = Wp4[(k + 2) * 256 + jg];
      const float4 w21 = Wp4[(k + 2) * 256 + jg + 128];
      const float4 w30 = Wp4[(k + 3) * 256 + jg];
      const float4 w31 = Wp4[(k + 3) * 256 + jg + 128];
      #pragma unroll
      for (int q = 0; q < 4; ++q) {
        const int bi = (bg << 2) + q;
        const float4 hv = *(const float4*)(&h_s[bi][k]);   // wave-broadcast read
        fma4(acc[q][0], hv.x, w00); fma4(acc[q][1], hv.x, w01);
        fma4(acc[q][0], hv.y, w10); fma4(acc[q][1], hv.y, w11);
        fma4(acc[q][0], hv.z, w20); fma4(acc[q][1], hv.z, w21);
        fma4(acc[q][0], hv.w, w30); fma4(acc[q][1], hv.w, w31);
      }
    }

    __syncthreads();   // all h reads done before overwrite

    #pragma unroll
    for (int q = 0; q < 4; ++q) {
      const int bi = (bg << 2) + q;
      #pragma unroll
      for (int u = 0; u < 2; ++u) {
        const float gi = acc[q][u].x;
        const float gf = acc[q][u].y;
        const float gg = acc[q][u].z;
        const float go = acc[q][u].w;
        const float si = 1.f / (1.f + expf(-gi));
        const float sf = 1.f / (1.f + expf(-gf));
        const float so = 1.f / (1.f + expf(-go));
        const float cn = sf * c_[q][u] + si * tanhf(gg);
        c_[q][u] = cn;
        h_s[bi][jg + (u << 7)] = so * tanhf(cn);
      }
    }
  }

  // write hn (each thread wrote exactly these h_s entries itself)
  #pragma unroll
  for (int q = 0; q < 4; ++q) {
    const int bi = (bg << 2) + q;
    const size_t b = (size_t)(b0 + bi);
    hnbuf[b * H_ + jg]       = h_s[bi][jg];
    hnbuf[b * H_ + jg + 128] = h_s[bi][jg + 128];
  }
}

// ---------------------------------------------------------------------------
// Kernel 3: fused MLP head. 512 blocks x 256 threads, 8 batches per block.
// relu(joint@W1+b1) -> relu(@W2+b2) -> @Wv+bv
// ---------------------------------------------------------------------------
__global__ __launch_bounds__(256) void mlp_kernel(
    const float* __restrict__ selfb, const float* __restrict__ hnbuf,
    const float* __restrict__ W1, const float* __restrict__ b1,
    const float* __restrict__ W2, const float* __restrict__ b2,
    const float* __restrict__ Wv, const float* __restrict__ bv,
    float* __restrict__ out) {
  const int tid = threadIdx.x;
  const int b0  = blockIdx.x << 3;      // 8 batches per block
  const int tb  = tid >> 6;             // 0..3
  const int tn  = tid & 63;             // float4 column group

  __shared__ float a0[8][264];          // joint (261 used)
  __shared__ float a1[8][M1_];
  __shared__ float a2[8][M2_];

  for (int i = tid; i < 8 * SS_; i += 256)
    a0[i / SS_][i % SS_] = selfb[b0 * SS_ + i];
  for (int i = tid; i < 8 * H_; i += 256)
    a0[i >> 8][SS_ + (i & 255)] = hnbuf[((size_t)b0 << 8) + i];
  __syncthreads();

  float4 acc[2][2];

  // ---- layer 1: K=261, N=512
  {
    const float4* W14 = (const float4*)W1;
    const float4* b14 = (const float4*)b1;
    #pragma unroll
    for (int q = 0; q < 2; ++q) { acc[q][0] = b14[tn]; acc[q][1] = b14[tn + 64]; }
    for (int k = 0; k < SS_ + H_; ++k) {
      const float4 w0 = W14[k * 128 + tn];
      const float4 w1 = W14[k * 128 + tn + 64];
      #pragma unroll
      for (int q = 0; q < 2; ++q) {
        const float av = a0[(tb << 1) + q][k];
        fma4(acc[q][0], av, w0);
        fma4(acc[q][1], av, w1);
      }
    }
    #pragma unroll
    for (int q = 0; q < 2; ++q) {
      const int bi = (tb << 1) + q;
      *(float4*)&a1[bi][tn << 2]        = relu4(acc[q][0]);
      *(float4*)&a1[bi][(tn + 64) << 2] = relu4(acc[q][1]);
    }
  }
  __syncthreads();

  // ---- layer 2: K=512, N=512
  {
    const float4* W24 = (const float4*)W2;
    const float4* b24 = (const float4*)b2;
    #pragma unroll
    for (int q = 0; q < 2; ++q) { acc[q][0] = b24[tn]; acc[q][1] = b24[tn + 64]; }
    for (int k = 0; k < M1_; ++k) {
      const float4 w0 = W24[k * 128 + tn];
      const float4 w1 = W24[k * 128 + tn + 64];
      #pragma unroll
      for (int q = 0; q < 2; ++q) {
        const float av = a1[(tb << 1) + q][k];
        fma4(acc[q][0], av, w0);
        fma4(acc[q][1], av, w1);
      }
    }
    #pragma unroll
    for (int q = 0; q < 2; ++q) {
      const int bi = (tb << 1) + q;
      *(float4*)&a2[bi][tn << 2]        = relu4(acc[q][0]);
      *(float4*)&a2[bi][(tn + 64) << 2] = relu4(acc[q][1]);
    }
  }
  __syncthreads();

  // ---- layer 3: K=512, N=81
  for (int idx = tid; idx < 8 * A_; idx += 256) {
    const int bi = idx / A_;
    const int n  = idx - bi * A_;
    float sum = bv[n];
    for (int k = 0; k < M2_; ++k)
      sum = fmaf(a2[bi][k], Wv[k * A_ + n], sum);
    out[(size_t)(b0 + bi) * A_ + n] = sum;
  }
}

// ---------------------------------------------------------------------------
extern "C" void kernel_launch(void* const* d_in, const int* in_sizes, int n_in,
                              void* d_out, int out_size, void* d_ws, size_t ws_size,
                              hipStream_t stream) {
  const float* state = (const float*)d_in[0];
  const float* W_ih  = (const float*)d_in[1];
  const float* W_hh  = (const float*)d_in[2];
  const float* b_ih  = (const float*)d_in[3];
  const float* b_hh  = (const float*)d_in[4];
  const float* W1    = (const float*)d_in[5];
  const float* b1    = (const float*)d_in[6];
  const float* W2    = (const float*)d_in[7];
  const float* b2    = (const float*)d_in[8];
  const float* Wv    = (const float*)d_in[9];
  const float* bv    = (const float*)d_in[10];
  float* out = (float*)d_out;

  // workspace layout (floats); total ~12.7 MB
  float* ws    = (float*)d_ws;
  float* Wp_hh = ws;                        // 256*1024  = 262144
  float* Wp_ih = Wp_hh + 262144;            // 7*1024    = 7168
  float* bsum  = Wp_ih + 7168;              // 1024
  float* xbuf  = bsum + 1024;               // 64*4096*7 = 1835008
  float* selfb = xbuf + 1835008;            // 4096*5    = 20480
  float* hnbuf = selfb + 20480;             // 4096*256  = 1048576

  pack_weights<<<dim3(1024), dim3(256), 0, stream>>>(W_ih, W_hh, b_ih, b_hh,
                                                     Wp_hh, Wp_ih, bsum);
  sort_gather<<<dim3(B_), dim3(64), 0, stream>>>(state, xbuf, selfb);
  lstm_kernel<<<dim3(B_ / 16), dim3(512), 0, stream>>>(xbuf, Wp_hh, Wp_ih, bsum, hnbuf);
  mlp_kernel<<<dim3(B_ / 8), dim3(256), 0, stream>>>(selfb, hnbuf, W1, b1, W2, b2,
                                                     Wv, bv, out);
}